// Round 4
// baseline (1468.227 us; speedup 1.0000x reference)
//
#include <hip/hip_runtime.h>

typedef unsigned short u16;
typedef unsigned int u32;

#define NPTS 131072
#define CD 128
#define KOFF 27
#define MMAP 65536
#define TOTE (KOFF * MMAP)  // 1769472 = 432 * 4096
#define LDAB 136            // LDS row stride (u16) for A/B tiles
#define LDC 132             // LDS row stride (u16) for C repack

__device__ __forceinline__ u16 f2bf(float f) {  // f32 -> bf16 RNE
  u32 u = __float_as_uint(f);
  u32 r = (u + 0x7fffu + ((u >> 16) & 1u)) >> 16;
  return (u16)r;
}

typedef __attribute__((ext_vector_type(8))) short bf16x8;
typedef __attribute__((ext_vector_type(4))) float f32x4;

// ---------------- dtype conversion ----------------
__global__ __launch_bounds__(256) void k_convert_x(const float* __restrict__ x,
                                                   u16* __restrict__ xb) {
  long i = ((long)blockIdx.x * 256 + threadIdx.x) * 8;
  float4 a = *(const float4*)(x + i);
  float4 b = *(const float4*)(x + i + 4);
  uint4 v;
  v.x = f2bf(a.x) | ((u32)f2bf(a.y) << 16);
  v.y = f2bf(a.z) | ((u32)f2bf(a.w) << 16);
  v.z = f2bf(b.x) | ((u32)f2bf(b.y) << 16);
  v.w = f2bf(b.z) | ((u32)f2bf(b.w) << 16);
  *(uint4*)(xb + i) = v;
}

// W [K][ci][co] f32 -> Wb [K][co][ci] bf16
__global__ __launch_bounds__(256) void k_convert_w(const float* __restrict__ W,
                                                   u16* __restrict__ Wb) {
  int idx = blockIdx.x * 256 + threadIdx.x;
  if (idx >= KOFF * 2048) return;
  int k = idx >> 11;
  int rem = idx & 2047;
  int co = rem >> 4;
  int cc = rem & 15;
  const float* ws = W + (long)k * (CD * CD) + (long)(cc * 8) * CD + co;
  u16 t[8];
#pragma unroll
  for (int j = 0; j < 8; ++j) t[j] = f2bf(ws[j * CD]);
  uint4 v;
  v.x = t[0] | ((u32)t[1] << 16);
  v.y = t[2] | ((u32)t[3] << 16);
  v.z = t[4] | ((u32)t[5] << 16);
  v.w = t[6] | ((u32)t[7] << 16);
  ((uint4*)Wb)[idx] = v;
}

// ---------------- pass 1: row histogram + (chunk,k)-bin histogram ----------------
__global__ __launch_bounds__(256) void k_histboth(const int* __restrict__ mo,
                                                  u32* __restrict__ hist,
                                                  u32* __restrict__ hist2,
                                                  int shift, int binsTot) {
  extern __shared__ u32 lh[];
  int t = threadIdx.x;
  for (int i = t; i < binsTot; i += 256) lh[i] = 0;
  __syncthreads();
  long base = (long)blockIdx.x * 4096;
#pragma unroll
  for (int j = 0; j < 16; ++j) {
    int idx = (int)(base + j * 256 + t);
    int row = mo[idx];
    atomicAdd(&hist[row], 1u);
    int bin = (row >> shift) * KOFF + (idx >> 16);
    atomicAdd(&lh[bin], 1u);
  }
  __syncthreads();
  for (int i = t; i < binsTot; i += 256)
    if (lh[i]) atomicAdd(&hist2[i], lh[i]);
}

// ---------------- scan of row histogram -> offs ----------------
__global__ __launch_bounds__(256) void k_scanA(const u32* __restrict__ hist,
                                               u32* __restrict__ offs,
                                               u32* __restrict__ bsum) {
  __shared__ u32 sh[256];
  int t = threadIdx.x, b = blockIdx.x, i = b * 256 + t;
  u32 v = hist[i];
  u32 run = v;
  sh[t] = run;
  __syncthreads();
  for (int d = 1; d < 256; d <<= 1) {
    u32 y = (t >= d) ? sh[t - d] : 0u;
    __syncthreads();
    run += y;
    sh[t] = run;
    __syncthreads();
  }
  offs[i] = run - v;
  if (t == 255) bsum[b] = run;
}

__global__ __launch_bounds__(512) void k_scanB(u32* __restrict__ bsum) {
  __shared__ u32 sh[512];
  int t = threadIdx.x;
  u32 v = bsum[t];
  u32 run = v;
  sh[t] = run;
  __syncthreads();
  for (int d = 1; d < 512; d <<= 1) {
    u32 y = (t >= d) ? sh[t - d] : 0u;
    __syncthreads();
    run += y;
    sh[t] = run;
    __syncthreads();
  }
  bsum[t] = run - v;
}

__global__ __launch_bounds__(256) void k_scanC(u32* __restrict__ offs,
                                               const u32* __restrict__ bsum) {
  int t = threadIdx.x, b = blockIdx.x, i = b * 256 + t;
  offs[i] += bsum[b];
  if (i == 0) offs[NPTS] = TOTE;
}

// ---------------- scan of bin histogram -> offs2, cur2, per-chunk tile prefix ----------------
__global__ __launch_bounds__(256) void k_scan2(const u32* __restrict__ hist2,
                                               u32* __restrict__ offs2,
                                               u32* __restrict__ cur2,
                                               u32* __restrict__ pre, int chunks) {
  __shared__ u32 lh[2048];
  __shared__ u32 tsum[256];
  int t = threadIdx.x;
  int binsTot = chunks * KOFF;
  for (int i = t; i < 2048; i += 256) lh[i] = (i < binsTot) ? hist2[i] : 0u;
  __syncthreads();
  u32 loc[8];
  u32 s = 0;
#pragma unroll
  for (int j = 0; j < 8; ++j) {
    loc[j] = s;
    s += lh[t * 8 + j];
  }
  tsum[t] = s;
  __syncthreads();
  u32 run = s;
  for (int d = 1; d < 256; d <<= 1) {
    u32 y = (t >= d) ? tsum[t - d] : 0u;
    __syncthreads();
    run += y;
    tsum[t] = run;
    __syncthreads();
  }
  u32 ex = run - s;
#pragma unroll
  for (int j = 0; j < 8; ++j) {
    int i = t * 8 + j;
    if (i < binsTot) {
      u32 v = ex + loc[j];
      offs2[i] = v;
      cur2[i] = v;
    }
  }
  if (t == 0) offs2[binsTot] = TOTE;
  __syncthreads();
  if (t < chunks) {
    u32 bp = 0;
    for (int k = 0; k < KOFF; ++k) {
      pre[t * 28 + k] = bp;
      bp += (lh[t * KOFF + k] + 63u) >> 6;
    }
    pre[t * 28 + KOFF] = bp;
  }
}

// ---------------- pass 2: rank (row-sorted position) + bin grouping via block reservation ----
__global__ __launch_bounds__(256) void k_rankplace(const int* __restrict__ mo,
                                                   const u32* __restrict__ offs,
                                                   u32* __restrict__ cur,
                                                   u32* __restrict__ rank,
                                                   u32* __restrict__ cur2,
                                                   u32* __restrict__ perm2e,
                                                   int shift, int binsTot) {
  extern __shared__ u32 sm[];  // cnt[binsTot], bas[binsTot]
  u32* cnt = sm;
  u32* bas = sm + binsTot;
  int t = threadIdx.x;
  for (int i = t; i < binsTot; i += 256) cnt[i] = 0;
  __syncthreads();
  long base = (long)blockIdx.x * 4096;
  int rows[16], bins[16];
#pragma unroll
  for (int j = 0; j < 16; ++j) {
    int idx = (int)(base + j * 256 + t);
    int row = mo[idx];
    rows[j] = row;
    int b = (row >> shift) * KOFF + (idx >> 16);
    bins[j] = b;
    atomicAdd(&cnt[b], 1u);
  }
  __syncthreads();
  for (int i = t; i < binsTot; i += 256) {
    u32 c = cnt[i];
    bas[i] = c ? atomicAdd(&cur2[i], c) : 0u;
  }
  __syncthreads();
  for (int i = t; i < binsTot; i += 256) cnt[i] = 0;
  __syncthreads();
#pragma unroll
  for (int j = 0; j < 16; ++j) {
    int idx = (int)(base + j * 256 + t);
    int b = bins[j];
    u32 lp = atomicAdd(&cnt[b], 1u);
    perm2e[bas[b] + lp] = (u32)idx;
    rank[idx] = offs[rows[j]] + atomicAdd(&cur[rows[j]], 1u);
  }
}

// ---------------- gather-GEMM: per chunk, blocks grouped by k-bin, rank-scatter rows ----------
__global__ __launch_bounds__(256) void k_gemm4(const u16* __restrict__ src,
                                               const u16* __restrict__ Wb,
                                               const int* __restrict__ mi,
                                               const u32* __restrict__ rank,
                                               const u32* __restrict__ perm2e,
                                               const u32* __restrict__ offs,
                                               const u32* __restrict__ offs2,
                                               const u32* __restrict__ pre,
                                               u16* __restrict__ contrib,
                                               int c, int R, u32 capRows) {
  __shared__ u16 As[64 * LDAB];
  __shared__ u16 Bs[128 * LDAB];
  __shared__ u32 sin[64];
  __shared__ u32 srow[64];
  const int t = threadIdx.x;
  const u32 b = blockIdx.x;
  const u32* cpre = pre + c * 28;
  if (b >= cpre[KOFF]) return;
  int k = 0;
  while (cpre[k + 1] <= b) ++k;
  const u32 bin = (u32)c * KOFF + k;
  const u32 P = offs2[bin] + (b - cpre[k]) * 64u;
  const u32 binEnd = offs2[bin + 1];
  const int nv = (int)((binEnd - P < 64u) ? (binEnd - P) : 64u);
  const u32 chunkStart = offs[(u32)c * (u32)R];

  if (t < 64) {
    u32 inr = 0, sr = 0xffffffffu;
    if (t < nv) {
      u32 e = perm2e[P + t];
      inr = (u32)mi[e];
      sr = rank[e] - chunkStart;
    }
    sin[t] = inr;
    srow[t] = sr;
  }
  const uint4* wsrc = (const uint4*)(Wb + (long)k * (CD * CD));
#pragma unroll
  for (int i = 0; i < 8; ++i) {
    int q = i * 256 + t;
    int co = q >> 4, cc = q & 15;
    *(uint4*)&Bs[co * LDAB + cc * 8] = wsrc[q];
  }
  __syncthreads();
#pragma unroll
  for (int i = 0; i < 4; ++i) {
    int q = i * 256 + t;
    int r = q >> 4, cc = q & 15;
    long row = sin[r];
    *(uint4*)&As[r * LDAB + cc * 8] = ((const uint4*)(src + row * CD))[cc];
  }
  __syncthreads();

  const int wave = t >> 6, lane = t & 63;
  const int lr = lane & 15, quad = lane >> 4;
  const int wm = (wave & 1) * 32;
  const int wn = (wave >> 1) * 64;
  f32x4 acc[2][4] = {};
#pragma unroll
  for (int kk = 0; kk < 4; ++kk) {
    bf16x8 a[2], bfr[4];
#pragma unroll
    for (int mt = 0; mt < 2; ++mt)
      a[mt] = *(const bf16x8*)&As[(wm + mt * 16 + lr) * LDAB + (kk * 4 + quad) * 8];
#pragma unroll
    for (int nt = 0; nt < 4; ++nt)
      bfr[nt] = *(const bf16x8*)&Bs[(wn + nt * 16 + lr) * LDAB + (kk * 4 + quad) * 8];
#pragma unroll
    for (int mt = 0; mt < 2; ++mt)
#pragma unroll
      for (int nt = 0; nt < 4; ++nt)
        acc[mt][nt] = __builtin_amdgcn_mfma_f32_16x16x32_bf16(a[mt], bfr[nt], acc[mt][nt], 0, 0, 0);
  }

  __syncthreads();
  u16* Cs = As;  // reuse As: 64*132 u16 fits
#pragma unroll
  for (int mt = 0; mt < 2; ++mt)
#pragma unroll
    for (int v = 0; v < 4; ++v) {
      int slot = wm + mt * 16 + quad * 4 + v;
#pragma unroll
      for (int nt = 0; nt < 4; ++nt)
        Cs[slot * LDC + wn + nt * 16 + lr] = f2bf(acc[mt][nt][v]);
    }
  __syncthreads();
#pragma unroll
  for (int i = 0; i < 4; ++i) {
    int q = i * 256 + t;
    int r = q >> 4, cc = q & 15;
    u32 rk = srow[r];
    if (rk < capRows)
      *(uint4*)(contrib + (size_t)rk * CD + cc * 8) = *(const uint4*)&Cs[r * LDC + cc * 8];
  }
}

// ---------------- per-chunk sequential segmented reduce + fused BN stats, bf16 acc out ------
__global__ __launch_bounds__(256) void k_segreduce4(const u16* __restrict__ contrib,
                                                    const u32* __restrict__ offs,
                                                    u32* __restrict__ accb,  // [NPTS][64] packed
                                                    float* __restrict__ stats,
                                                    int c, int R) {
  const int wave = threadIdx.x >> 6, lane = threadIdx.x & 63;
  const int w = blockIdx.x * 4 + wave;  // 2048 waves
  const int rbase = c * R;
  const u32 chunkStart = offs[rbase];
  float sx = 0.f, sx2 = 0.f, sy = 0.f, sy2 = 0.f;
  for (int row = rbase + w; row < rbase + R; row += 2048) {
    u32 s0 = offs[row] - chunkStart, s1 = offs[row + 1] - chunkStart;
    float a0 = 0.f, b0 = 0.f, a1 = 0.f, b1 = 0.f;
    u32 e = s0;
    for (; e + 2 <= s1; e += 2) {
      u32 d0 = ((const u32*)(contrib + (size_t)e * CD))[lane];
      u32 d1 = ((const u32*)(contrib + (size_t)(e + 1) * CD))[lane];
      a0 += __uint_as_float(d0 << 16);
      b0 += __uint_as_float(d0 & 0xffff0000u);
      a1 += __uint_as_float(d1 << 16);
      b1 += __uint_as_float(d1 & 0xffff0000u);
    }
    if (e < s1) {
      u32 d0 = ((const u32*)(contrib + (size_t)e * CD))[lane];
      a0 += __uint_as_float(d0 << 16);
      b0 += __uint_as_float(d0 & 0xffff0000u);
    }
    float cx = a0 + a1, cy = b0 + b1;
    accb[(size_t)row * 64 + lane] = (u32)f2bf(cx) | ((u32)f2bf(cy) << 16);
    sx += cx;
    sx2 += cx * cx;
    sy += cy;
    sy2 += cy * cy;
  }
  __shared__ float sh[1024];
  sh[threadIdx.x] = sx;
  sh[256 + threadIdx.x] = sx2;
  sh[512 + threadIdx.x] = sy;
  sh[768 + threadIdx.x] = sy2;
  __syncthreads();
  if (threadIdx.x < 64) {
    int l = threadIdx.x;
    float vx = sh[l] + sh[l + 64] + sh[l + 128] + sh[l + 192];
    float vx2 = sh[256 + l] + sh[256 + l + 64] + sh[256 + l + 128] + sh[256 + l + 192];
    float vy = sh[512 + l] + sh[512 + l + 64] + sh[512 + l + 128] + sh[512 + l + 192];
    float vy2 = sh[768 + l] + sh[768 + l + 64] + sh[768 + l + 128] + sh[768 + l + 192];
    atomicAdd(&stats[2 * l], vx);
    atomicAdd(&stats[128 + 2 * l], vx2);
    atomicAdd(&stats[2 * l + 1], vy);
    atomicAdd(&stats[128 + 2 * l + 1], vy2);
  }
}

// ---------------- BN finalize / apply ----------------
__global__ void k_finalize(const float* __restrict__ stats, const float* __restrict__ gamma,
                           const float* __restrict__ beta, float* __restrict__ scsh) {
  int c = threadIdx.x;
  float mean = stats[c] * (1.f / NPTS);
  float var = stats[128 + c] * (1.f / NPTS) - mean * mean;
  float sc = rsqrtf(var + 1e-5f) * gamma[c];
  scsh[c] = sc;
  scsh[128 + c] = beta[c] - mean * sc;
}

__device__ __forceinline__ float elu(float v) { return v > 0.f ? v : expf(v) - 1.f; }

__global__ __launch_bounds__(256) void k_apply_mid(const u16* __restrict__ accb,
                                                   const float* __restrict__ scsh,
                                                   u16* __restrict__ y) {
  long i = ((long)blockIdx.x * 256 + threadIdx.x) * 8;
  int c = (int)(i & 127);
  uint4 a = *(const uint4*)(accb + i);
  u32 w[4] = {a.x, a.y, a.z, a.w};
  uint4 o;
  u32 ov[4];
#pragma unroll
  for (int j = 0; j < 4; ++j) {
    float lo = __uint_as_float(w[j] << 16);
    float hi = __uint_as_float(w[j] & 0xffff0000u);
    float r0 = elu(lo * scsh[c + 2 * j] + scsh[128 + c + 2 * j]);
    float r1 = elu(hi * scsh[c + 2 * j + 1] + scsh[129 + c + 2 * j]);
    ov[j] = (u32)f2bf(r0) | ((u32)f2bf(r1) << 16);
  }
  o.x = ov[0];
  o.y = ov[1];
  o.z = ov[2];
  o.w = ov[3];
  *(uint4*)(y + i) = o;
}

__global__ __launch_bounds__(256) void k_apply_final(const u16* __restrict__ accb,
                                                     const float* __restrict__ scsh,
                                                     const float* __restrict__ x,
                                                     float* __restrict__ out) {
  long i = ((long)blockIdx.x * 256 + threadIdx.x) * 8;
  int c = (int)(i & 127);
  uint4 a = *(const uint4*)(accb + i);
  u32 w[4] = {a.x, a.y, a.z, a.w};
  float4 rx0 = *(const float4*)(x + i);
  float4 rx1 = *(const float4*)(x + i + 4);
  float rx[8] = {rx0.x, rx0.y, rx0.z, rx0.w, rx1.x, rx1.y, rx1.z, rx1.w};
  float res[8];
#pragma unroll
  for (int j = 0; j < 4; ++j) {
    float lo = __uint_as_float(w[j] << 16);
    float hi = __uint_as_float(w[j] & 0xffff0000u);
    res[2 * j] = elu(lo * scsh[c + 2 * j] + scsh[128 + c + 2 * j] + rx[2 * j]);
    res[2 * j + 1] = elu(hi * scsh[c + 2 * j + 1] + scsh[129 + c + 2 * j] + rx[2 * j + 1]);
  }
  float4 o0 = {res[0], res[1], res[2], res[3]};
  float4 o1 = {res[4], res[5], res[6], res[7]};
  *(float4*)(out + i) = o0;
  *(float4*)(out + i + 4) = o1;
}

// ---------------- host ----------------
extern "C" void kernel_launch(void* const* d_in, const int* in_sizes, int n_in,
                              void* d_out, int out_size, void* d_ws, size_t ws_size,
                              hipStream_t stream) {
  const float* x = (const float*)d_in[0];
  const float* W1 = (const float*)d_in[1];
  const float* g1 = (const float*)d_in[2];
  const float* b1 = (const float*)d_in[3];
  const float* W2 = (const float*)d_in[4];
  const float* g2 = (const float*)d_in[5];
  const float* b2 = (const float*)d_in[6];
  const int* m1i = (const int*)d_in[7];
  const int* m1o = (const int*)d_in[8];
  const int* m2i = (const int*)d_in[9];
  const int* m2o = (const int*)d_in[10];
  float* out = (float*)d_out;

  // pick chunk count: fixed footprint + contrib(cap) must fit ws
  auto pad = [](size_t b) { return (b + 255) & ~(size_t)255; };
  size_t fixedB = pad((size_t)NPTS * CD * 2) * 2 /*xb,yb*/ +
                  pad((size_t)KOFF * CD * CD * 2) * 2 /*Wb*/ +
                  pad((size_t)NPTS * CD * 2) /*accb*/ + pad((size_t)NPTS * 4) * 2 /*hist,cur*/ +
                  pad(((size_t)NPTS + 1) * 4) /*offs*/ + pad(256 * 4) * 2 /*stats,scsh*/ +
                  pad(512 * 4) /*bsum*/ + pad((size_t)TOTE * 4) * 2 /*rank,perm2e*/ + 65536;
  int chunks = 64;
  u32 capRows = TOTE / 64 + 32768;
  for (int tryc = 4; tryc <= 64; tryc <<= 1) {
    u32 cap = (u32)(TOTE / tryc) + 32768u;
    size_t binB = pad((size_t)(tryc * KOFF + 64) * 4) * 3 + pad((size_t)tryc * 28 * 4);
    if (fixedB + binB + (size_t)cap * 256 <= ws_size) {
      chunks = tryc;
      capRows = cap;
      break;
    }
  }
  int shift = 17;
  {
    int lg = 0;
    while ((1 << lg) < chunks) ++lg;
    shift = 17 - lg;
  }
  const int R = NPTS / chunks;
  const int binsTot = chunks * KOFF;
  const u32 maxB = capRows / 64 + KOFF;

  char* base = (char*)d_ws;
  size_t off = 0;
  auto alloc = [&](size_t bytes) -> void* {
    void* r = base + off;
    off = (off + bytes + 255) & ~(size_t)255;
    return r;
  };
  u16* xb = (u16*)alloc((size_t)NPTS * CD * 2);
  u16* yb = (u16*)alloc((size_t)NPTS * CD * 2);
  u16* Wb1 = (u16*)alloc((size_t)KOFF * CD * CD * 2);
  u16* Wb2 = (u16*)alloc((size_t)KOFF * CD * CD * 2);
  u32* accb = (u32*)alloc((size_t)NPTS * CD * 2);
  // contiguous memset region: hist, cur, hist2, stats
  u32* hist = (u32*)alloc((size_t)NPTS * 4);
  u32* cur = (u32*)alloc((size_t)NPTS * 4);
  u32* hist2 = (u32*)alloc((size_t)(binsTot + 64) * 4);
  float* stats = (float*)alloc(256 * 4);
  size_t msSize = (size_t)((char*)base + off - (char*)hist);
  u32* cur2 = (u32*)alloc((size_t)(binsTot + 64) * 4);
  u32* offs2 = (u32*)alloc((size_t)(binsTot + 64) * 4);
  u32* pre = (u32*)alloc((size_t)chunks * 28 * 4);
  u32* offs = (u32*)alloc(((size_t)NPTS + 1) * 4);
  float* scsh = (float*)alloc(256 * 4);
  u32* bsum = (u32*)alloc(512 * 4);
  u32* rank = (u32*)alloc((size_t)TOTE * 4);
  u32* perm2e = (u32*)alloc((size_t)TOTE * 4);
  u16* contrib = (u16*)alloc((size_t)capRows * CD * 2);

  k_convert_x<<<(NPTS * CD) / 2048, 256, 0, stream>>>(x, xb);
  k_convert_w<<<(KOFF * 2048 + 255) / 256, 256, 0, stream>>>(W1, Wb1);
  k_convert_w<<<(KOFF * 2048 + 255) / 256, 256, 0, stream>>>(W2, Wb2);

  auto run_conv = [&](const u16* srcm, const u16* Wbm, const int* mi, const int* mo) {
    hipMemsetAsync(hist, 0, msSize, stream);
    k_histboth<<<432, 256, binsTot * 4, stream>>>(mo, hist, hist2, shift, binsTot);
    k_scanA<<<512, 256, 0, stream>>>(hist, offs, bsum);
    k_scanB<<<1, 512, 0, stream>>>(bsum);
    k_scanC<<<512, 256, 0, stream>>>(offs, bsum);
    k_scan2<<<1, 256, 0, stream>>>(hist2, offs2, cur2, pre, chunks);
    k_rankplace<<<432, 256, 2 * binsTot * 4, stream>>>(mo, offs, cur, rank, cur2, perm2e,
                                                       shift, binsTot);
    for (int c = 0; c < chunks; ++c) {
      k_gemm4<<<maxB, 256, 0, stream>>>(srcm, Wbm, mi, rank, perm2e, offs, offs2, pre,
                                        contrib, c, R, capRows);
      k_segreduce4<<<512, 256, 0, stream>>>(contrib, offs, accb, stats, c, R);
    }
  };

  run_conv(xb, Wb1, m1i, m1o);
  k_finalize<<<1, 128, 0, stream>>>(stats, g1, b1, scsh);
  k_apply_mid<<<(NPTS * CD) / 2048, 256, 0, stream>>>((const u16*)accb, scsh, yb);

  run_conv(yb, Wb2, m2i, m2o);
  k_finalize<<<1, 128, 0, stream>>>(stats, g2, b2, scsh);
  k_apply_final<<<(NPTS * CD) / 2048, 256, 0, stream>>>((const u16*)accb, scsh, x, out);
}